// Round 7
// baseline (292.335 us; speedup 1.0000x reference)
//
#include <hip/hip_runtime.h>
#include <math.h>

#define BATCH 8
#define NPTS 4096
#define CHAN 128
#define KNN 16
#define SPLIT 4
#define CHUNK (NPTS / SPLIT)   // 1024 candidates per chunk-block
#define ISPLIT 4               // internal candidate split (4 quarters)
#define QCH (CHUNK / ISPLIT)   // 256 candidates per thread
#define PTILE 128              // points per block
#define EPC 24                 // slow-path survivor buffer capacity
#define RSPLIT 4
#define RCHUNK (NPTS / RSPLIT) // 1024 scores, 4 KB LDS

typedef unsigned long long u64;

// Monotone key: ascending u64 == (d2 ascending, idx ascending).
// Ties in d2 break toward lower index == lax.top_k stable order.
__device__ __forceinline__ u64 pack_key(float d2, int idx) {
  unsigned b = __float_as_uint(d2);
  b ^= (unsigned)((int)b >> 31) | 0x80000000u;  // order-preserving fp32 map
  return ((u64)b << 32) | (unsigned)idx;
}

// Reference d2: inner = ((x0*y0 + x1*y1) + x2*y2) fp32 no-fma (numpy einsum
// order); d2 = (sq_n + sq_m) - 2*inner. Bit-exact vs JAX reference.
__device__ __forceinline__ float d2_ref(float4 q, float ppx, float ppy,
                                        float ppz, float psq) {
  float inner = __fadd_rn(__fadd_rn(__fmul_rn(ppx, q.x), __fmul_rn(ppy, q.y)),
                          __fmul_rn(ppz, q.z));
  return __fsub_rn(__fadd_rn(psq, q.w), __fmul_rn(2.0f, inner));
}

// ----- u64 compare-exchange machinery (epilogues + k1b) --------------------
__device__ __forceinline__ void ce_asc(u64& x, u64& y) {
  bool sw = y < x;
  u64 lo = sw ? y : x;
  u64 hi = sw ? x : y;
  x = lo;
  y = hi;
}

// Batcher merge-exchange sort of 16 u64 keys, ascending. 63 CE.
__device__ __forceinline__ void batcher_sort16_u64(u64 a[16]) {
#define CE(i, j) ce_asc(a[i], a[j])
  CE(0, 8); CE(1, 9); CE(2, 10); CE(3, 11);
  CE(4, 12); CE(5, 13); CE(6, 14); CE(7, 15);
  CE(0, 4); CE(1, 5); CE(2, 6); CE(3, 7);
  CE(8, 12); CE(9, 13); CE(10, 14); CE(11, 15);
  CE(4, 8); CE(5, 9); CE(6, 10); CE(7, 11);
  CE(0, 2); CE(1, 3); CE(4, 6); CE(5, 7);
  CE(8, 10); CE(9, 11); CE(12, 14); CE(13, 15);
  CE(2, 8); CE(3, 9); CE(6, 12); CE(7, 13);
  CE(2, 4); CE(3, 5); CE(6, 8); CE(7, 9); CE(10, 12); CE(11, 13);
  CE(0, 1); CE(2, 3); CE(4, 5); CE(6, 7);
  CE(8, 9); CE(10, 11); CE(12, 13); CE(14, 15);
  CE(1, 8); CE(3, 10); CE(5, 12); CE(7, 14);
  CE(1, 4); CE(3, 6); CE(5, 8); CE(7, 10); CE(9, 12); CE(11, 14);
  CE(1, 2); CE(3, 4); CE(5, 6); CE(7, 8); CE(9, 10); CE(11, 12); CE(13, 14);
#undef CE
}

// Bitonic sort of 32 u64 keys, ascending. 240 CE (slow path only).
__device__ __forceinline__ void bitonic_sort32(u64 a[32]) {
#pragma unroll
  for (int k = 2; k <= 32; k <<= 1) {
#pragma unroll
    for (int j = k >> 1; j > 0; j >>= 1) {
#pragma unroll
      for (int i = 0; i < 32; ++i) {
        int l = i ^ j;
        if (l > i) {
          if ((i & k) == 0) ce_asc(a[i], a[l]);
          else              ce_asc(a[l], a[i]);
        }
      }
    }
  }
}

// T, A both sorted ascending. T <- lowest-16 of (T ∪ A), sorted ascending.
__device__ __forceinline__ void merge_keep16(u64 T[16], const u64 A[16]) {
  u64 nt[16];
#pragma unroll
  for (int i = 0; i < 16; ++i) {
    u64 a = A[15 - i];
    nt[i] = (a < T[i]) ? a : T[i];
  }
#pragma unroll
  for (int j = 8; j > 0; j >>= 1) {
#pragma unroll
    for (int i = 0; i < 16; ++i) {
      int l = i ^ j;
      if (l > i) ce_asc(nt[i], nt[l]);
    }
  }
#pragma unroll
  for (int i = 0; i < 16; ++i) T[i] = nt[i];
}

// ----- i32 packed-key machinery (hot phase 1) ------------------------------
// Packed key = (d2bits & ~255) | local_idx (8-bit). Signed-i32 ascending ==
// (trunc(d2), idx) ascending for all d2 >= 0 (negatives sort below all
// positives -> always selected -> exact epilogue fixes internal order).
// CE = v_min_i32 + v_max_i32 = 2 VALU.
__device__ __forceinline__ void ce_i32(int& x, int& y) {
  int lo = (x < y) ? x : y;
  int hi = (x < y) ? y : x;
  x = lo;
  y = hi;
}

// Batcher merge-exchange sort of 16 i32 keys, ascending. 63 CE.
__device__ __forceinline__ void batcher_sort16_i32(int a[16]) {
#define CE(i, j) ce_i32(a[i], a[j])
  CE(0, 8); CE(1, 9); CE(2, 10); CE(3, 11);
  CE(4, 12); CE(5, 13); CE(6, 14); CE(7, 15);
  CE(0, 4); CE(1, 5); CE(2, 6); CE(3, 7);
  CE(8, 12); CE(9, 13); CE(10, 14); CE(11, 15);
  CE(4, 8); CE(5, 9); CE(6, 10); CE(7, 11);
  CE(0, 2); CE(1, 3); CE(4, 6); CE(5, 7);
  CE(8, 10); CE(9, 11); CE(12, 14); CE(13, 15);
  CE(2, 8); CE(3, 9); CE(6, 12); CE(7, 13);
  CE(2, 4); CE(3, 5); CE(6, 8); CE(7, 9); CE(10, 12); CE(11, 13);
  CE(0, 1); CE(2, 3); CE(4, 5); CE(6, 7);
  CE(8, 9); CE(10, 11); CE(12, 13); CE(14, 15);
  CE(1, 8); CE(3, 10); CE(5, 12); CE(7, 14);
  CE(1, 4); CE(3, 6); CE(5, 8); CE(7, 10); CE(9, 12); CE(11, 14);
  CE(1, 2); CE(3, 4); CE(5, 6); CE(7, 8); CE(9, 10); CE(11, 12); CE(13, 14);
#undef CE
}

// T, A sorted ascending (i32). T <- lowest-16 of (T ∪ A). 80 VALU.
__device__ __forceinline__ void merge_keep16_i32(int T[16], const int A[16]) {
  int nt[16];
#pragma unroll
  for (int i = 0; i < 16; ++i) {
    int a = A[15 - i];
    nt[i] = (a < T[i]) ? a : T[i];
  }
#pragma unroll
  for (int j = 8; j > 0; j >>= 1) {
#pragma unroll
    for (int i = 0; i < 16; ++i) {
      int l = i ^ j;
      if (l > i) ce_i32(nt[i], nt[l]);
    }
  }
#pragma unroll
  for (int i = 0; i < 16; ++i) T[i] = nt[i];
}

// ---------------------------------------------------------------------------
// Kernel 1a: per-chunk 16-NN partials as sorted u64 keys.
// Round-7: stall reduction (R6 showed real VALU busy ~43 of 133 us; the
// VALUBusy counter is ~2x inflated by the gfx94x SIMD-16 formula).
//   * Register prefetch pipeline: batch k+1's 16 float4s are loaded into
//     named registers while batch k's ~238-VALU sort/merge runs (WAR-only
//     dep). Covers the ~120-cyc LDS latency in-wave, independent of
//     occupancy. VGPR target ~110 < 128 cap from waves_per_eu(4,4).
//   * LDS 40 KB -> 32 KB: slow-path scratch uses u8 local indices
//     (QCH=256 fits) -> 12 KB, union'd with the 16 KB combine staging.
//     4 blocks/CU with 32 KB slack (was exactly 160 KB -> padding risk).
// Exactness: tau superset + exact r17 guard; fast path rebuilds exact u64
// keys; slow path rescans {trunc <= tau} -> bit-identical to full-u64 path.
// ---------------------------------------------------------------------------
__global__ __attribute__((amdgpu_waves_per_eu(4, 4)))
__launch_bounds__(512) void knn_partial_kernel(
    const float* __restrict__ x, u64* __restrict__ pkey) {
  const int s = blockIdx.x % SPLIT;
  const int ntile = (blockIdx.x / SPLIT) % (NPTS / PTILE);
  const int b = blockIdx.x / (SPLIT * (NPTS / PTILE));
  const int p = threadIdx.x & (PTILE - 1);
  const int q4 = threadIdx.x >> 7;  // quarter 0..3 (wave-uniform: 2 waves/q)
  __shared__ float4 xs[CHUNK];        // 16 KB (x, y, z, sq)
  __shared__ u64 ubuf[2048];          // 16 KB: u8 scratch(12K) ∪ staging(16K)

  const float* xb = x + (size_t)b * 3 * NPTS;
  for (int i = threadIdx.x; i < CHUNK; i += 512) {
    int gm = s * CHUNK + i;
    float px = xb[gm];
    float py = xb[NPTS + gm];
    float pz = xb[2 * NPTS + gm];
    float sq = __fadd_rn(__fadd_rn(__fmul_rn(px, px), __fmul_rn(py, py)),
                         __fmul_rn(pz, pz));
    xs[i] = make_float4(px, py, pz, sq);
  }

  const int n = ntile * PTILE + p;
  float ppx = xb[n];
  float ppy = xb[NPTS + n];
  float ppz = xb[2 * NPTS + n];
  float psq = __fadd_rn(__fadd_rn(__fmul_rn(ppx, ppx), __fmul_rn(ppy, ppy)),
                        __fmul_rn(ppz, ppz));
  __syncthreads();

  const int cbase = q4 * QCH;

  // ---- Phase 1: top-16 packed keys + exact 17th (r17), reg-prefetched ----
  int T[16];
#pragma unroll
  for (int i = 0; i < 16; ++i) T[i] = 0x7FFFFFFF;  // sentinel > any real key
  int r17 = 0x7FFFFFFF;

  float4 qc[16];  // current batch, register-resident (prefetch pipeline)
#pragma unroll
  for (int t = 0; t < 16; ++t) qc[t] = xs[cbase + t];

#pragma unroll 1
  for (int base = 0; base < QCH; base += 16) {
    int A[16];
#pragma unroll
    for (int t = 0; t < 16; ++t) {
      int bits = __float_as_int(d2_ref(qc[t], ppx, ppy, ppz, psq));
      A[t] = (bits & 0xFFFFFF00) | (base + t);
    }
    // issue next batch's loads now; WAR-only dep on the d2s above, and the
    // ~238-VALU sort/merge below hides the LDS latency.
    if (base + 16 < QCH) {
#pragma unroll
      for (int t = 0; t < 16; ++t) qc[t] = xs[cbase + base + 16 + t];
    }
    batcher_sort16_i32(A);
    // 17th smallest of (T ∪ A), both sorted: min_i max(T[i], A[15-i])
    int u[16];
#pragma unroll
    for (int i = 0; i < 16; ++i) {
      int a = A[15 - i];
      u[i] = (T[i] < a) ? a : T[i];  // max
    }
#pragma unroll
    for (int w = 8; w > 0; w >>= 1) {
#pragma unroll
      for (int i = 0; i < 16; ++i) {
        if (i < w) u[i] = (u[i] < u[i + w]) ? u[i] : u[i + w];  // min
      }
    }
    r17 = (r17 < u[0]) ? r17 : u[0];
    merge_keep16_i32(T, A);
  }

  const int tau = T[15] & 0xFFFFFF00;
  const bool slow = ((r17 & 0xFFFFFF00) == tau);

  // ---- Epilogue: exact u64 top-16 keys ----
  u64 K[16];
  if (!slow) {
    // fast: T is the exact top-16 set; rebuild exact keys, sort.
#pragma unroll
    for (int j = 0; j < 16; ++j) {
      int loc = cbase + (T[j] & 255);
      float4 q = xs[loc];
      float d2 = d2_ref(q, ppx, ppy, ppz, psq);
      K[j] = pack_key(d2, s * CHUNK + loc);
    }
    batcher_sort16_u64(K);
  } else {
    // slow: collect all candidates with trunc <= tau, exact sort, keep 16.
    unsigned char* myb =
        reinterpret_cast<unsigned char*>(ubuf) + (unsigned)threadIdx.x * EPC;
    int cnt = 0;
#pragma unroll 4
    for (int m = 0; m < QCH; ++m) {
      float4 q = xs[cbase + m];
      int tb = __float_as_int(d2_ref(q, ppx, ppy, ppz, psq)) & 0xFFFFFF00;
      if (tb <= tau) {
        myb[cnt < EPC - 1 ? cnt : EPC - 1] = (unsigned char)m;
        ++cnt;
      }
    }
    u64 KK[32];
#pragma unroll
    for (int j = 0; j < EPC; ++j) {
      int loc = cbase + myb[j];  // u8: always < QCH, garbage past cnt masked
      float4 q = xs[loc];
      float d2 = d2_ref(q, ppx, ppy, ppz, psq);
      u64 k = pack_key(d2, s * CHUNK + loc);
      KK[j] = (j < cnt) ? k : ~0ull;
    }
#pragma unroll
    for (int j = EPC; j < 32; ++j) KK[j] = ~0ull;
    bitonic_sort32(KK);
#pragma unroll
    for (int j = 0; j < 16; ++j) K[j] = KK[j];
  }

  // ---- combine quarters: chain q1,q2,q3 stage -> q0 merges ----
  __syncthreads();  // scratch lifetime ends; staging view reuses ubuf
  u64(*L)[PTILE] = reinterpret_cast<u64(*)[PTILE]>(ubuf);
#pragma unroll 1
  for (int r = 1; r <= 3; ++r) {
    if (q4 == r) {
#pragma unroll
      for (int j = 0; j < 16; ++j) L[j][p] = K[j];
    }
    __syncthreads();
    if (q4 == 0) {
      u64 A64[16];
#pragma unroll
      for (int j = 0; j < 16; ++j) A64[j] = L[j][p];
      merge_keep16(K, A64);
    }
    __syncthreads();
  }
  if (q4 == 0) {
    u64* pb = pkey + ((size_t)(b * SPLIT + s) * KNN) * NPTS + n;
#pragma unroll
    for (int j = 0; j < 16; ++j) pb[(size_t)j * NPTS] = K[j];
  }
}

// ---------------------------------------------------------------------------
// Kernel 1b: merge SPLIT sorted key lists -> global top-16, then fp32 score
// with numpy's pairwise order. Keys unique -> order of merging irrelevant ->
// exactness holds. Also zeroes the rank counters.
// grid: BATCH*NPTS/64 = 512 blocks x 64 thr (covers all 256 CUs; the old
// 128x256 grid left half the device idle on this latency-bound kernel).
// ---------------------------------------------------------------------------
__global__ __launch_bounds__(64) void merge_score_kernel(
    const float* __restrict__ x, const u64* __restrict__ pkey,
    float* __restrict__ score, int* __restrict__ cnt) {
  const int b = blockIdx.x / (NPTS / 64);
  const int n = (blockIdx.x % (NPTS / 64)) * 64 + threadIdx.x;

  cnt[(size_t)b * NPTS + n] = 0;  // zero rank counters (was zero_kernel)

  u64 T[16];
  {
    const u64* pb = pkey + ((size_t)(b * SPLIT + 0) * KNN) * NPTS + n;
#pragma unroll
    for (int j = 0; j < 16; ++j) T[j] = pb[(size_t)j * NPTS];
  }
#pragma unroll
  for (int s = 1; s < SPLIT; ++s) {
    const u64* pb = pkey + ((size_t)(b * SPLIT + s) * KNN) * NPTS + n;
    u64 A[16];
#pragma unroll
    for (int j = 0; j < 16; ++j) A[j] = pb[(size_t)j * NPTS];
    merge_keep16(T, A);
  }

  const float* xb = x + (size_t)b * 3 * NPTS;
  float ppx = xb[n];
  float ppy = xb[NPTS + n];
  float ppz = xb[2 * NPTS + n];

  float nx[KNN], ny[KNN], nz[KNN];
#pragma unroll
  for (int j = 0; j < KNN; ++j) {
    int idx = (int)(unsigned)T[j];
    nx[j] = xb[idx];
    ny[j] = xb[NPTS + idx];
    nz[j] = xb[2 * NPTS + idx];
  }

  // numpy fp32 pairwise sum over (3,16): per d, r_j = a_j + a_{j+8},
  // P_d = ((r0+r1)+(r2+r3)) + ((r4+r5)+(r6+r7)); score = (P0+P1)+P2.
  float P[3];
#pragma unroll
  for (int d = 0; d < 3; ++d) {
    const float pc = (d == 0) ? ppx : ((d == 1) ? ppy : ppz);
    float r[8];
#pragma unroll
    for (int j = 0; j < 8; ++j) {
      float c0 = (d == 0) ? nx[j] : ((d == 1) ? ny[j] : nz[j]);
      float c1 = (d == 0) ? nx[j + 8] : ((d == 1) ? ny[j + 8] : nz[j + 8]);
      float e0 = __fsub_rn(c0, pc);
      float e1 = __fsub_rn(c1, pc);
      r[j] = __fadd_rn(__fmul_rn(e0, e0), __fmul_rn(e1, e1));
    }
    float t0 = __fadd_rn(r[0], r[1]);
    float t1 = __fadd_rn(r[2], r[3]);
    float t2 = __fadd_rn(r[4], r[5]);
    float t3 = __fadd_rn(r[6], r[7]);
    P[d] = __fadd_rn(__fadd_rn(t0, t1), __fadd_rn(t2, t3));
  }
  score[(size_t)b * NPTS + n] =
      __fadd_rn(__fadd_rn(P[0], P[1]), P[2]);
}

// ---------------------------------------------------------------------------
// Kernel 2b: partial counting rank over an m-chunk, atomicAdd into cnt.
// rank(n) = #{m : s[m]>s[n] or (s[m]==s[n] and m<n)} == stable desc argsort.
// ---------------------------------------------------------------------------
__global__ __launch_bounds__(256) void rank_partial_kernel(
    const float* __restrict__ score, int* __restrict__ cnt) {
  const int s = blockIdx.x % RSPLIT;
  const int ntile = (blockIdx.x / RSPLIT) % (NPTS / 256);
  const int b = blockIdx.x / (RSPLIT * (NPTS / 256));
  __shared__ float ss[RCHUNK];

  const float* sb = score + (size_t)b * NPTS;
  for (int i = threadIdx.x; i < RCHUNK; i += 256)
    ss[i] = sb[s * RCHUNK + i];

  const int n = ntile * 256 + threadIdx.x;
  const float sn = sb[n];
  __syncthreads();

  int c = 0;
#pragma unroll 8
  for (int mm = 0; mm < RCHUNK; ++mm) {
    float sm = ss[mm];
    int gm = s * RCHUNK + mm;
    c += (sm > sn) || (sm == sn && gm < n);
  }
  atomicAdd(&cnt[(size_t)b * NPTS + n], c);
}

// ---------------------------------------------------------------------------
// Kernel 2c: scatter selected points into rank order.
// ---------------------------------------------------------------------------
__global__ __launch_bounds__(256) void rank_scatter_kernel(
    const int* __restrict__ cnt, int* __restrict__ sel, int npts) {
  int t = blockIdx.x * 256 + threadIdx.x;  // over BATCH*NPTS
  int b = t / NPTS;
  int n = t % NPTS;
  int c = cnt[t];
  if (c < npts) sel[(size_t)b * npts + c] = n;
}

// ---------------------------------------------------------------------------
// Kernel 3: gather xyz then features into the concatenated flat output.
// ---------------------------------------------------------------------------
__global__ __launch_bounds__(256) void gather_kernel(
    const float* __restrict__ x, const float* __restrict__ y,
    const int* __restrict__ sel, float* __restrict__ out, int npts,
    int total0, int total) {
  int tid = blockIdx.x * blockDim.x + threadIdx.x;
  if (tid >= total) return;
  if (tid < total0) {
    int j = tid % npts;
    int rest = tid / npts;
    int d = rest % 3;
    int b = rest / 3;
    int src = sel[b * npts + j];
    out[tid] = x[((size_t)b * 3 + d) * NPTS + src];
  } else {
    int t = tid - total0;
    int j = t % npts;
    int rest = t / npts;
    int c = rest % CHAN;
    int b = rest / CHAN;
    int src = sel[b * npts + j];
    out[tid] = y[((size_t)b * CHAN + c) * NPTS + src];
  }
}

extern "C" void kernel_launch(void* const* d_in, const int* in_sizes, int n_in,
                              void* d_out, int out_size, void* d_ws,
                              size_t ws_size, hipStream_t stream) {
  const float* x = (const float*)d_in[0];
  const float* y = (const float*)d_in[1];
  float* out = (float*)d_out;

  const int npts = out_size / (BATCH * (3 + CHAN));

  // workspace layout:
  char* w = (char*)d_ws;
  u64* pkey = (u64*)w;                       // B*S*16*N u64 = 16.78 MB
  w += sizeof(u64) * (size_t)BATCH * SPLIT * KNN * NPTS;
  float* score = (float*)w;                  // B*N f32
  w += sizeof(float) * (size_t)BATCH * NPTS;
  int* cnt = (int*)w;                        // B*N i32
  w += sizeof(int) * (size_t)BATCH * NPTS;
  int* sel = (int*)w;                        // B*npts i32

  knn_partial_kernel<<<BATCH * (NPTS / PTILE) * SPLIT, 512, 0, stream>>>(
      x, pkey);
  merge_score_kernel<<<BATCH * NPTS / 64, 64, 0, stream>>>(x, pkey, score,
                                                           cnt);
  rank_partial_kernel<<<BATCH * (NPTS / 256) * RSPLIT, 256, 0, stream>>>(
      score, cnt);
  rank_scatter_kernel<<<BATCH * NPTS / 256, 256, 0, stream>>>(cnt, sel, npts);

  const int total0 = BATCH * 3 * npts;
  gather_kernel<<<(out_size + 255) / 256, 256, 0, stream>>>(
      x, y, sel, out, npts, total0, out_size);
}

// Round 8
// 256.272 us; speedup vs baseline: 1.1407x; 1.1407x over previous
//
#include <hip/hip_runtime.h>
#include <math.h>

#define BATCH 8
#define NPTS 4096
#define CHAN 128
#define KNN 16
#define SPLIT 4
#define CHUNK (NPTS / SPLIT)   // 1024 candidates per chunk-block
#define ISPLIT 4               // internal candidate split (4 quarters)
#define QCH (CHUNK / ISPLIT)   // 256 candidates per thread
#define PTILE 128              // points per block
#define EPC 24                 // slow-path survivor buffer capacity
#define RSPLIT 4
#define RCHUNK (NPTS / RSPLIT) // 1024 scores, 4 KB LDS

typedef unsigned long long u64;

// Monotone key: ascending u64 == (d2 ascending, idx ascending).
// Ties in d2 break toward lower index == lax.top_k stable order.
__device__ __forceinline__ u64 pack_key(float d2, int idx) {
  unsigned b = __float_as_uint(d2);
  b ^= (unsigned)((int)b >> 31) | 0x80000000u;  // order-preserving fp32 map
  return ((u64)b << 32) | (unsigned)idx;
}

// Reference d2: inner = ((x0*y0 + x1*y1) + x2*y2) fp32 no-fma (numpy einsum
// order); d2 = (sq_n + sq_m) - 2*inner. Bit-exact vs JAX reference.
__device__ __forceinline__ float d2_ref(float4 q, float ppx, float ppy,
                                        float ppz, float psq) {
  float inner = __fadd_rn(__fadd_rn(__fmul_rn(ppx, q.x), __fmul_rn(ppy, q.y)),
                          __fmul_rn(ppz, q.z));
  return __fsub_rn(__fadd_rn(psq, q.w), __fmul_rn(2.0f, inner));
}

// ----- u64 compare-exchange machinery (epilogues + k1b) --------------------
__device__ __forceinline__ void ce_asc(u64& x, u64& y) {
  bool sw = y < x;
  u64 lo = sw ? y : x;
  u64 hi = sw ? x : y;
  x = lo;
  y = hi;
}

// Batcher merge-exchange sort of 16 u64 keys, ascending. 63 CE.
__device__ __forceinline__ void batcher_sort16_u64(u64 a[16]) {
#define CE(i, j) ce_asc(a[i], a[j])
  CE(0, 8); CE(1, 9); CE(2, 10); CE(3, 11);
  CE(4, 12); CE(5, 13); CE(6, 14); CE(7, 15);
  CE(0, 4); CE(1, 5); CE(2, 6); CE(3, 7);
  CE(8, 12); CE(9, 13); CE(10, 14); CE(11, 15);
  CE(4, 8); CE(5, 9); CE(6, 10); CE(7, 11);
  CE(0, 2); CE(1, 3); CE(4, 6); CE(5, 7);
  CE(8, 10); CE(9, 11); CE(12, 14); CE(13, 15);
  CE(2, 8); CE(3, 9); CE(6, 12); CE(7, 13);
  CE(2, 4); CE(3, 5); CE(6, 8); CE(7, 9); CE(10, 12); CE(11, 13);
  CE(0, 1); CE(2, 3); CE(4, 5); CE(6, 7);
  CE(8, 9); CE(10, 11); CE(12, 13); CE(14, 15);
  CE(1, 8); CE(3, 10); CE(5, 12); CE(7, 14);
  CE(1, 4); CE(3, 6); CE(5, 8); CE(7, 10); CE(9, 12); CE(11, 14);
  CE(1, 2); CE(3, 4); CE(5, 6); CE(7, 8); CE(9, 10); CE(11, 12); CE(13, 14);
#undef CE
}

// Bitonic sort of 32 u64 keys, ascending. 240 CE (slow path only).
__device__ __forceinline__ void bitonic_sort32(u64 a[32]) {
#pragma unroll
  for (int k = 2; k <= 32; k <<= 1) {
#pragma unroll
    for (int j = k >> 1; j > 0; j >>= 1) {
#pragma unroll
      for (int i = 0; i < 32; ++i) {
        int l = i ^ j;
        if (l > i) {
          if ((i & k) == 0) ce_asc(a[i], a[l]);
          else              ce_asc(a[l], a[i]);
        }
      }
    }
  }
}

// T, A both sorted ascending. T <- lowest-16 of (T ∪ A), sorted ascending.
__device__ __forceinline__ void merge_keep16(u64 T[16], const u64 A[16]) {
  u64 nt[16];
#pragma unroll
  for (int i = 0; i < 16; ++i) {
    u64 a = A[15 - i];
    nt[i] = (a < T[i]) ? a : T[i];
  }
#pragma unroll
  for (int j = 8; j > 0; j >>= 1) {
#pragma unroll
    for (int i = 0; i < 16; ++i) {
      int l = i ^ j;
      if (l > i) ce_asc(nt[i], nt[l]);
    }
  }
#pragma unroll
  for (int i = 0; i < 16; ++i) T[i] = nt[i];
}

// ----- i32 packed-key machinery (hot phase 1) ------------------------------
// Packed key = (d2bits & ~255) | local_idx (8-bit). Signed-i32 ascending ==
// (trunc(d2), idx) ascending for all d2 >= 0 (negatives sort below all
// positives -> always selected -> exact epilogue fixes internal order).
// CE = v_min_i32 + v_max_i32 = 2 VALU.
__device__ __forceinline__ void ce_i32(int& x, int& y) {
  int lo = (x < y) ? x : y;
  int hi = (x < y) ? y : x;
  x = lo;
  y = hi;
}

// Batcher merge-exchange sort of 16 i32 keys, ascending. 63 CE.
__device__ __forceinline__ void batcher_sort16_i32(int a[16]) {
#define CE(i, j) ce_i32(a[i], a[j])
  CE(0, 8); CE(1, 9); CE(2, 10); CE(3, 11);
  CE(4, 12); CE(5, 13); CE(6, 14); CE(7, 15);
  CE(0, 4); CE(1, 5); CE(2, 6); CE(3, 7);
  CE(8, 12); CE(9, 13); CE(10, 14); CE(11, 15);
  CE(4, 8); CE(5, 9); CE(6, 10); CE(7, 11);
  CE(0, 2); CE(1, 3); CE(4, 6); CE(5, 7);
  CE(8, 10); CE(9, 11); CE(12, 14); CE(13, 15);
  CE(2, 8); CE(3, 9); CE(6, 12); CE(7, 13);
  CE(2, 4); CE(3, 5); CE(6, 8); CE(7, 9); CE(10, 12); CE(11, 13);
  CE(0, 1); CE(2, 3); CE(4, 5); CE(6, 7);
  CE(8, 9); CE(10, 11); CE(12, 13); CE(14, 15);
  CE(1, 8); CE(3, 10); CE(5, 12); CE(7, 14);
  CE(1, 4); CE(3, 6); CE(5, 8); CE(7, 10); CE(9, 12); CE(11, 14);
  CE(1, 2); CE(3, 4); CE(5, 6); CE(7, 8); CE(9, 10); CE(11, 12); CE(13, 14);
#undef CE
}

// T, A sorted ascending (i32). T <- lowest-16 of (T ∪ A). 80 VALU.
__device__ __forceinline__ void merge_keep16_i32(int T[16], const int A[16]) {
  int nt[16];
#pragma unroll
  for (int i = 0; i < 16; ++i) {
    int a = A[15 - i];
    nt[i] = (a < T[i]) ? a : T[i];
  }
#pragma unroll
  for (int j = 8; j > 0; j >>= 1) {
#pragma unroll
    for (int i = 0; i < 16; ++i) {
      int l = i ^ j;
      if (l > i) ce_i32(nt[i], nt[l]);
    }
  }
#pragma unroll
  for (int i = 0; i < 16; ++i) T[i] = nt[i];
}

// ---------------------------------------------------------------------------
// Kernel 1a: per-chunk 16-NN partials as sorted u64 keys.
// Round-8: revert the R7 register-prefetch (it spilled: WRITE_SIZE 16->325 MB
// scratch traffic under the 128-VGPR cap). Instead: #pragma unroll 2 on the
// batch loop + waves_per_eu(3,4) (cap ~170 VGPR) -- the scheduler may hoist
// batch k+1's ds_reads over batch k's sort at whatever register depth fits,
// rather than being forced to hold a named 64-VGPR array live.
// Keeps from R7: u8 slow-path scratch -> LDS 32 KB total.
// Exactness: tau superset + exact r17 guard; fast path rebuilds exact u64
// keys; slow path rescans {trunc <= tau} -> bit-identical to full-u64 path.
// ---------------------------------------------------------------------------
__global__ __attribute__((amdgpu_waves_per_eu(3, 4)))
__launch_bounds__(512) void knn_partial_kernel(
    const float* __restrict__ x, u64* __restrict__ pkey) {
  const int s = blockIdx.x % SPLIT;
  const int ntile = (blockIdx.x / SPLIT) % (NPTS / PTILE);
  const int b = blockIdx.x / (SPLIT * (NPTS / PTILE));
  const int p = threadIdx.x & (PTILE - 1);
  const int q4 = threadIdx.x >> 7;  // quarter 0..3 (wave-uniform: 2 waves/q)
  __shared__ float4 xs[CHUNK];        // 16 KB (x, y, z, sq)
  __shared__ u64 ubuf[2048];          // 16 KB: u8 scratch(12K) ∪ staging(16K)

  const float* xb = x + (size_t)b * 3 * NPTS;
  for (int i = threadIdx.x; i < CHUNK; i += 512) {
    int gm = s * CHUNK + i;
    float px = xb[gm];
    float py = xb[NPTS + gm];
    float pz = xb[2 * NPTS + gm];
    float sq = __fadd_rn(__fadd_rn(__fmul_rn(px, px), __fmul_rn(py, py)),
                         __fmul_rn(pz, pz));
    xs[i] = make_float4(px, py, pz, sq);
  }

  const int n = ntile * PTILE + p;
  float ppx = xb[n];
  float ppy = xb[NPTS + n];
  float ppz = xb[2 * NPTS + n];
  float psq = __fadd_rn(__fadd_rn(__fmul_rn(ppx, ppx), __fmul_rn(ppy, ppy)),
                        __fmul_rn(ppz, ppz));
  __syncthreads();

  const int cbase = q4 * QCH;

  // ---- Phase 1: top-16 packed keys + exact 17th (r17) ----
  int T[16];
#pragma unroll
  for (int i = 0; i < 16; ++i) T[i] = 0x7FFFFFFF;  // sentinel > any real key
  int r17 = 0x7FFFFFFF;

#pragma unroll 2
  for (int base = 0; base < QCH; base += 16) {
    int A[16];
#pragma unroll
    for (int t = 0; t < 16; ++t) {
      float4 q = xs[cbase + base + t];
      int bits = __float_as_int(d2_ref(q, ppx, ppy, ppz, psq));
      A[t] = (bits & 0xFFFFFF00) | (base + t);
    }
    batcher_sort16_i32(A);
    // 17th smallest of (T ∪ A), both sorted: min_i max(T[i], A[15-i])
    int u[16];
#pragma unroll
    for (int i = 0; i < 16; ++i) {
      int a = A[15 - i];
      u[i] = (T[i] < a) ? a : T[i];  // max
    }
#pragma unroll
    for (int w = 8; w > 0; w >>= 1) {
#pragma unroll
      for (int i = 0; i < 16; ++i) {
        if (i < w) u[i] = (u[i] < u[i + w]) ? u[i] : u[i + w];  // min
      }
    }
    r17 = (r17 < u[0]) ? r17 : u[0];
    merge_keep16_i32(T, A);
  }

  const int tau = T[15] & 0xFFFFFF00;
  const bool slow = ((r17 & 0xFFFFFF00) == tau);

  // ---- Epilogue: exact u64 top-16 keys ----
  u64 K[16];
  if (!slow) {
    // fast: T is the exact top-16 set; rebuild exact keys, sort.
#pragma unroll
    for (int j = 0; j < 16; ++j) {
      int loc = cbase + (T[j] & 255);
      float4 q = xs[loc];
      float d2 = d2_ref(q, ppx, ppy, ppz, psq);
      K[j] = pack_key(d2, s * CHUNK + loc);
    }
    batcher_sort16_u64(K);
  } else {
    // slow: collect all candidates with trunc <= tau, exact sort, keep 16.
    unsigned char* myb =
        reinterpret_cast<unsigned char*>(ubuf) + (unsigned)threadIdx.x * EPC;
    int cnt = 0;
#pragma unroll 4
    for (int m = 0; m < QCH; ++m) {
      float4 q = xs[cbase + m];
      int tb = __float_as_int(d2_ref(q, ppx, ppy, ppz, psq)) & 0xFFFFFF00;
      if (tb <= tau) {
        myb[cnt < EPC - 1 ? cnt : EPC - 1] = (unsigned char)m;
        ++cnt;
      }
    }
    u64 KK[32];
#pragma unroll
    for (int j = 0; j < EPC; ++j) {
      int loc = cbase + myb[j];  // u8 always < QCH; garbage past cnt masked
      float4 q = xs[loc];
      float d2 = d2_ref(q, ppx, ppy, ppz, psq);
      u64 k = pack_key(d2, s * CHUNK + loc);
      KK[j] = (j < cnt) ? k : ~0ull;
    }
#pragma unroll
    for (int j = EPC; j < 32; ++j) KK[j] = ~0ull;
    bitonic_sort32(KK);
#pragma unroll
    for (int j = 0; j < 16; ++j) K[j] = KK[j];
  }

  // ---- combine quarters: chain q1,q2,q3 stage -> q0 merges ----
  __syncthreads();  // scratch lifetime ends; staging view reuses ubuf
  u64(*L)[PTILE] = reinterpret_cast<u64(*)[PTILE]>(ubuf);
#pragma unroll 1
  for (int r = 1; r <= 3; ++r) {
    if (q4 == r) {
#pragma unroll
      for (int j = 0; j < 16; ++j) L[j][p] = K[j];
    }
    __syncthreads();
    if (q4 == 0) {
      u64 A64[16];
#pragma unroll
      for (int j = 0; j < 16; ++j) A64[j] = L[j][p];
      merge_keep16(K, A64);
    }
    __syncthreads();
  }
  if (q4 == 0) {
    u64* pb = pkey + ((size_t)(b * SPLIT + s) * KNN) * NPTS + n;
#pragma unroll
    for (int j = 0; j < 16; ++j) pb[(size_t)j * NPTS] = K[j];
  }
}

// ---------------------------------------------------------------------------
// Kernel 1b: merge SPLIT sorted key lists -> global top-16, then fp32 score
// with numpy's pairwise order. Keys unique -> order of merging irrelevant ->
// exactness holds. Also zeroes the rank counters.
// grid: BATCH*NPTS/64 = 512 blocks x 64 thr (covers all 256 CUs).
// ---------------------------------------------------------------------------
__global__ __launch_bounds__(64) void merge_score_kernel(
    const float* __restrict__ x, const u64* __restrict__ pkey,
    float* __restrict__ score, int* __restrict__ cnt) {
  const int b = blockIdx.x / (NPTS / 64);
  const int n = (blockIdx.x % (NPTS / 64)) * 64 + threadIdx.x;

  cnt[(size_t)b * NPTS + n] = 0;  // zero rank counters (was zero_kernel)

  u64 T[16];
  {
    const u64* pb = pkey + ((size_t)(b * SPLIT + 0) * KNN) * NPTS + n;
#pragma unroll
    for (int j = 0; j < 16; ++j) T[j] = pb[(size_t)j * NPTS];
  }
#pragma unroll
  for (int s = 1; s < SPLIT; ++s) {
    const u64* pb = pkey + ((size_t)(b * SPLIT + s) * KNN) * NPTS + n;
    u64 A[16];
#pragma unroll
    for (int j = 0; j < 16; ++j) A[j] = pb[(size_t)j * NPTS];
    merge_keep16(T, A);
  }

  const float* xb = x + (size_t)b * 3 * NPTS;
  float ppx = xb[n];
  float ppy = xb[NPTS + n];
  float ppz = xb[2 * NPTS + n];

  float nx[KNN], ny[KNN], nz[KNN];
#pragma unroll
  for (int j = 0; j < KNN; ++j) {
    int idx = (int)(unsigned)T[j];
    nx[j] = xb[idx];
    ny[j] = xb[NPTS + idx];
    nz[j] = xb[2 * NPTS + idx];
  }

  // numpy fp32 pairwise sum over (3,16): per d, r_j = a_j + a_{j+8},
  // P_d = ((r0+r1)+(r2+r3)) + ((r4+r5)+(r6+r7)); score = (P0+P1)+P2.
  float P[3];
#pragma unroll
  for (int d = 0; d < 3; ++d) {
    const float pc = (d == 0) ? ppx : ((d == 1) ? ppy : ppz);
    float r[8];
#pragma unroll
    for (int j = 0; j < 8; ++j) {
      float c0 = (d == 0) ? nx[j] : ((d == 1) ? ny[j] : nz[j]);
      float c1 = (d == 0) ? nx[j + 8] : ((d == 1) ? ny[j + 8] : nz[j + 8]);
      float e0 = __fsub_rn(c0, pc);
      float e1 = __fsub_rn(c1, pc);
      r[j] = __fadd_rn(__fmul_rn(e0, e0), __fmul_rn(e1, e1));
    }
    float t0 = __fadd_rn(r[0], r[1]);
    float t1 = __fadd_rn(r[2], r[3]);
    float t2 = __fadd_rn(r[4], r[5]);
    float t3 = __fadd_rn(r[6], r[7]);
    P[d] = __fadd_rn(__fadd_rn(t0, t1), __fadd_rn(t2, t3));
  }
  score[(size_t)b * NPTS + n] =
      __fadd_rn(__fadd_rn(P[0], P[1]), P[2]);
}

// ---------------------------------------------------------------------------
// Kernel 2b: partial counting rank over an m-chunk, atomicAdd into cnt.
// rank(n) = #{m : s[m]>s[n] or (s[m]==s[n] and m<n)} == stable desc argsort.
// ---------------------------------------------------------------------------
__global__ __launch_bounds__(256) void rank_partial_kernel(
    const float* __restrict__ score, int* __restrict__ cnt) {
  const int s = blockIdx.x % RSPLIT;
  const int ntile = (blockIdx.x / RSPLIT) % (NPTS / 256);
  const int b = blockIdx.x / (RSPLIT * (NPTS / 256));
  __shared__ float ss[RCHUNK];

  const float* sb = score + (size_t)b * NPTS;
  for (int i = threadIdx.x; i < RCHUNK; i += 256)
    ss[i] = sb[s * RCHUNK + i];

  const int n = ntile * 256 + threadIdx.x;
  const float sn = sb[n];
  __syncthreads();

  int c = 0;
#pragma unroll 8
  for (int mm = 0; mm < RCHUNK; ++mm) {
    float sm = ss[mm];
    int gm = s * RCHUNK + mm;
    c += (sm > sn) || (sm == sn && gm < n);
  }
  atomicAdd(&cnt[(size_t)b * NPTS + n], c);
}

// ---------------------------------------------------------------------------
// Kernel 2c: scatter selected points into rank order.
// ---------------------------------------------------------------------------
__global__ __launch_bounds__(256) void rank_scatter_kernel(
    const int* __restrict__ cnt, int* __restrict__ sel, int npts) {
  int t = blockIdx.x * 256 + threadIdx.x;  // over BATCH*NPTS
  int b = t / NPTS;
  int n = t % NPTS;
  int c = cnt[t];
  if (c < npts) sel[(size_t)b * npts + c] = n;
}

// ---------------------------------------------------------------------------
// Kernel 3: gather xyz then features into the concatenated flat output.
// ---------------------------------------------------------------------------
__global__ __launch_bounds__(256) void gather_kernel(
    const float* __restrict__ x, const float* __restrict__ y,
    const int* __restrict__ sel, float* __restrict__ out, int npts,
    int total0, int total) {
  int tid = blockIdx.x * blockDim.x + threadIdx.x;
  if (tid >= total) return;
  if (tid < total0) {
    int j = tid % npts;
    int rest = tid / npts;
    int d = rest % 3;
    int b = rest / 3;
    int src = sel[b * npts + j];
    out[tid] = x[((size_t)b * 3 + d) * NPTS + src];
  } else {
    int t = tid - total0;
    int j = t % npts;
    int rest = t / npts;
    int c = rest % CHAN;
    int b = rest / CHAN;
    int src = sel[b * npts + j];
    out[tid] = y[((size_t)b * CHAN + c) * NPTS + src];
  }
}

extern "C" void kernel_launch(void* const* d_in, const int* in_sizes, int n_in,
                              void* d_out, int out_size, void* d_ws,
                              size_t ws_size, hipStream_t stream) {
  const float* x = (const float*)d_in[0];
  const float* y = (const float*)d_in[1];
  float* out = (float*)d_out;

  const int npts = out_size / (BATCH * (3 + CHAN));

  // workspace layout:
  char* w = (char*)d_ws;
  u64* pkey = (u64*)w;                       // B*S*16*N u64 = 16.78 MB
  w += sizeof(u64) * (size_t)BATCH * SPLIT * KNN * NPTS;
  float* score = (float*)w;                  // B*N f32
  w += sizeof(float) * (size_t)BATCH * NPTS;
  int* cnt = (int*)w;                        // B*N i32
  w += sizeof(int) * (size_t)BATCH * NPTS;
  int* sel = (int*)w;                        // B*npts i32

  knn_partial_kernel<<<BATCH * (NPTS / PTILE) * SPLIT, 512, 0, stream>>>(
      x, pkey);
  merge_score_kernel<<<BATCH * NPTS / 64, 64, 0, stream>>>(x, pkey, score,
                                                           cnt);
  rank_partial_kernel<<<BATCH * (NPTS / 256) * RSPLIT, 256, 0, stream>>>(
      score, cnt);
  rank_scatter_kernel<<<BATCH * NPTS / 256, 256, 0, stream>>>(cnt, sel, npts);

  const int total0 = BATCH * 3 * npts;
  gather_kernel<<<(out_size + 255) / 256, 256, 0, stream>>>(
      x, y, sel, out, npts, total0, out_size);
}

// Round 9
// 250.105 us; speedup vs baseline: 1.1688x; 1.0247x over previous
//
#include <hip/hip_runtime.h>
#include <math.h>

#define BATCH 8
#define NPTS 4096
#define CHAN 128
#define KNN 16
#define SPLIT 4
#define CHUNK (NPTS / SPLIT)   // 1024 candidates per chunk-block
#define ISPLIT 4               // internal candidate split (4 quarters)
#define QCH (CHUNK / ISPLIT)   // 256 candidates per thread
#define PTILE 128              // points per block
#define EPC 24                 // slow-path survivor buffer capacity
#define RSPLIT 4
#define RCHUNK (NPTS / RSPLIT) // 1024 scores, 4 KB LDS

typedef unsigned long long u64;

// Monotone key: ascending u64 == (d2 ascending, idx ascending).
// Ties in d2 break toward lower index == lax.top_k stable order.
__device__ __forceinline__ u64 pack_key(float d2, int idx) {
  unsigned b = __float_as_uint(d2);
  b ^= (unsigned)((int)b >> 31) | 0x80000000u;  // order-preserving fp32 map
  return ((u64)b << 32) | (unsigned)idx;
}

// Reference d2: inner = ((x0*y0 + x1*y1) + x2*y2) fp32 no-fma (numpy einsum
// order); d2 = (sq_n + sq_m) - 2*inner. Bit-exact vs JAX reference.
__device__ __forceinline__ float d2_ref(float4 q, float ppx, float ppy,
                                        float ppz, float psq) {
  float inner = __fadd_rn(__fadd_rn(__fmul_rn(ppx, q.x), __fmul_rn(ppy, q.y)),
                          __fmul_rn(ppz, q.z));
  return __fsub_rn(__fadd_rn(psq, q.w), __fmul_rn(2.0f, inner));
}

// ----- u64 compare-exchange machinery (epilogues + k1b) --------------------
__device__ __forceinline__ void ce_asc(u64& x, u64& y) {
  bool sw = y < x;
  u64 lo = sw ? y : x;
  u64 hi = sw ? x : y;
  x = lo;
  y = hi;
}

// Batcher merge-exchange sort of 16 u64 keys, ascending. 63 CE.
__device__ __forceinline__ void batcher_sort16_u64(u64 a[16]) {
#define CE(i, j) ce_asc(a[i], a[j])
  CE(0, 8); CE(1, 9); CE(2, 10); CE(3, 11);
  CE(4, 12); CE(5, 13); CE(6, 14); CE(7, 15);
  CE(0, 4); CE(1, 5); CE(2, 6); CE(3, 7);
  CE(8, 12); CE(9, 13); CE(10, 14); CE(11, 15);
  CE(4, 8); CE(5, 9); CE(6, 10); CE(7, 11);
  CE(0, 2); CE(1, 3); CE(4, 6); CE(5, 7);
  CE(8, 10); CE(9, 11); CE(12, 14); CE(13, 15);
  CE(2, 8); CE(3, 9); CE(6, 12); CE(7, 13);
  CE(2, 4); CE(3, 5); CE(6, 8); CE(7, 9); CE(10, 12); CE(11, 13);
  CE(0, 1); CE(2, 3); CE(4, 5); CE(6, 7);
  CE(8, 9); CE(10, 11); CE(12, 13); CE(14, 15);
  CE(1, 8); CE(3, 10); CE(5, 12); CE(7, 14);
  CE(1, 4); CE(3, 6); CE(5, 8); CE(7, 10); CE(9, 12); CE(11, 14);
  CE(1, 2); CE(3, 4); CE(5, 6); CE(7, 8); CE(9, 10); CE(11, 12); CE(13, 14);
#undef CE
}

// Bitonic sort of 32 u64 keys, ascending. 240 CE (slow path only).
__device__ __forceinline__ void bitonic_sort32(u64 a[32]) {
#pragma unroll
  for (int k = 2; k <= 32; k <<= 1) {
#pragma unroll
    for (int j = k >> 1; j > 0; j >>= 1) {
#pragma unroll
      for (int i = 0; i < 32; ++i) {
        int l = i ^ j;
        if (l > i) {
          if ((i & k) == 0) ce_asc(a[i], a[l]);
          else              ce_asc(a[l], a[i]);
        }
      }
    }
  }
}

// T, A both sorted ascending. T <- lowest-16 of (T ∪ A), sorted ascending.
__device__ __forceinline__ void merge_keep16(u64 T[16], const u64 A[16]) {
  u64 nt[16];
#pragma unroll
  for (int i = 0; i < 16; ++i) {
    u64 a = A[15 - i];
    nt[i] = (a < T[i]) ? a : T[i];
  }
#pragma unroll
  for (int j = 8; j > 0; j >>= 1) {
#pragma unroll
    for (int i = 0; i < 16; ++i) {
      int l = i ^ j;
      if (l > i) ce_asc(nt[i], nt[l]);
    }
  }
#pragma unroll
  for (int i = 0; i < 16; ++i) T[i] = nt[i];
}

// ----- i32 packed-key machinery (hot phase 1) ------------------------------
// Packed key = (d2bits & ~255) | local_idx (8-bit). Signed-i32 ascending ==
// (trunc(d2), idx) ascending for all d2 >= 0 (negatives sort below all
// positives -> always selected -> exact epilogue fixes internal order).
// CE = v_min_i32 + v_max_i32 = 2 VALU.
__device__ __forceinline__ void ce_i32(int& x, int& y) {
  int lo = (x < y) ? x : y;
  int hi = (x < y) ? y : x;
  x = lo;
  y = hi;
}

// Batcher merge-exchange sort of 16 i32 keys, ascending. 63 CE.
__device__ __forceinline__ void batcher_sort16_i32(int a[16]) {
#define CE(i, j) ce_i32(a[i], a[j])
  CE(0, 8); CE(1, 9); CE(2, 10); CE(3, 11);
  CE(4, 12); CE(5, 13); CE(6, 14); CE(7, 15);
  CE(0, 4); CE(1, 5); CE(2, 6); CE(3, 7);
  CE(8, 12); CE(9, 13); CE(10, 14); CE(11, 15);
  CE(4, 8); CE(5, 9); CE(6, 10); CE(7, 11);
  CE(0, 2); CE(1, 3); CE(4, 6); CE(5, 7);
  CE(8, 10); CE(9, 11); CE(12, 14); CE(13, 15);
  CE(2, 8); CE(3, 9); CE(6, 12); CE(7, 13);
  CE(2, 4); CE(3, 5); CE(6, 8); CE(7, 9); CE(10, 12); CE(11, 13);
  CE(0, 1); CE(2, 3); CE(4, 5); CE(6, 7);
  CE(8, 9); CE(10, 11); CE(12, 13); CE(14, 15);
  CE(1, 8); CE(3, 10); CE(5, 12); CE(7, 14);
  CE(1, 4); CE(3, 6); CE(5, 8); CE(7, 10); CE(9, 12); CE(11, 14);
  CE(1, 2); CE(3, 4); CE(5, 6); CE(7, 8); CE(9, 10); CE(11, 12); CE(13, 14);
#undef CE
}

// T, A sorted ascending (i32). T <- lowest-16 of (T ∪ A). 80 VALU.
__device__ __forceinline__ void merge_keep16_i32(int T[16], const int A[16]) {
  int nt[16];
#pragma unroll
  for (int i = 0; i < 16; ++i) {
    int a = A[15 - i];
    nt[i] = (a < T[i]) ? a : T[i];
  }
#pragma unroll
  for (int j = 8; j > 0; j >>= 1) {
#pragma unroll
    for (int i = 0; i < 16; ++i) {
      int l = i ^ j;
      if (l > i) ce_i32(nt[i], nt[l]);
    }
  }
#pragma unroll
  for (int i = 0; i < 16; ++i) T[i] = nt[i];
}

// ---------------------------------------------------------------------------
// Kernel 1a: per-chunk 16-NN partials as sorted u64 keys.
// Round-9: REMOVE the amdgpu_waves_per_eu attribute. Post-mortem of R6-R8
// showed its MAX arg caps residency at 4 waves/EU = 2 blocks/CU (measured
// occupancy 26.5% ~ the cap minus tail), while grid (1024 blocks = 4/CU),
// LDS (32KB x 4 = 128KB <= 160KB) and VGPR (52) all permit 4 blocks/CU =
// 8 waves/EU. Device-work floor: VALU ~39us + LDS-pipe ~41us, overlappable
// across waves -> ~50-60us at full residency vs 144us measured at 2/SIMD.
// The attribute was installed in R0 against VGPR inflation (then 88); at
// VGPR 52 it is pure cap. unroll reverted to 1 (R8's unroll-2 was -8%: code
// bloat, no pipelining, VGPR unchanged -> compiler won't SW-pipeline this).
// Exactness: tau superset + exact r17 guard; fast path rebuilds exact u64
// keys; slow path rescans {trunc <= tau} -> bit-identical to full-u64 path.
// ---------------------------------------------------------------------------
__global__ __launch_bounds__(512) void knn_partial_kernel(
    const float* __restrict__ x, u64* __restrict__ pkey) {
  const int s = blockIdx.x % SPLIT;
  const int ntile = (blockIdx.x / SPLIT) % (NPTS / PTILE);
  const int b = blockIdx.x / (SPLIT * (NPTS / PTILE));
  const int p = threadIdx.x & (PTILE - 1);
  const int q4 = threadIdx.x >> 7;  // quarter 0..3 (wave-uniform: 2 waves/q)
  __shared__ float4 xs[CHUNK];        // 16 KB (x, y, z, sq)
  __shared__ u64 ubuf[2048];          // 16 KB: u8 scratch(12K) ∪ staging(16K)

  const float* xb = x + (size_t)b * 3 * NPTS;
  for (int i = threadIdx.x; i < CHUNK; i += 512) {
    int gm = s * CHUNK + i;
    float px = xb[gm];
    float py = xb[NPTS + gm];
    float pz = xb[2 * NPTS + gm];
    float sq = __fadd_rn(__fadd_rn(__fmul_rn(px, px), __fmul_rn(py, py)),
                         __fmul_rn(pz, pz));
    xs[i] = make_float4(px, py, pz, sq);
  }

  const int n = ntile * PTILE + p;
  float ppx = xb[n];
  float ppy = xb[NPTS + n];
  float ppz = xb[2 * NPTS + n];
  float psq = __fadd_rn(__fadd_rn(__fmul_rn(ppx, ppx), __fmul_rn(ppy, ppy)),
                        __fmul_rn(ppz, ppz));
  __syncthreads();

  const int cbase = q4 * QCH;

  // ---- Phase 1: top-16 packed keys + exact 17th (r17) ----
  int T[16];
#pragma unroll
  for (int i = 0; i < 16; ++i) T[i] = 0x7FFFFFFF;  // sentinel > any real key
  int r17 = 0x7FFFFFFF;

#pragma unroll 1
  for (int base = 0; base < QCH; base += 16) {
    int A[16];
#pragma unroll
    for (int t = 0; t < 16; ++t) {
      float4 q = xs[cbase + base + t];
      int bits = __float_as_int(d2_ref(q, ppx, ppy, ppz, psq));
      A[t] = (bits & 0xFFFFFF00) | (base + t);
    }
    batcher_sort16_i32(A);
    // 17th smallest of (T ∪ A), both sorted: min_i max(T[i], A[15-i])
    int u[16];
#pragma unroll
    for (int i = 0; i < 16; ++i) {
      int a = A[15 - i];
      u[i] = (T[i] < a) ? a : T[i];  // max
    }
#pragma unroll
    for (int w = 8; w > 0; w >>= 1) {
#pragma unroll
      for (int i = 0; i < 16; ++i) {
        if (i < w) u[i] = (u[i] < u[i + w]) ? u[i] : u[i + w];  // min
      }
    }
    r17 = (r17 < u[0]) ? r17 : u[0];
    merge_keep16_i32(T, A);
  }

  const int tau = T[15] & 0xFFFFFF00;
  const bool slow = ((r17 & 0xFFFFFF00) == tau);

  // ---- Epilogue: exact u64 top-16 keys ----
  u64 K[16];
  if (!slow) {
    // fast: T is the exact top-16 set; rebuild exact keys, sort.
#pragma unroll
    for (int j = 0; j < 16; ++j) {
      int loc = cbase + (T[j] & 255);
      float4 q = xs[loc];
      float d2 = d2_ref(q, ppx, ppy, ppz, psq);
      K[j] = pack_key(d2, s * CHUNK + loc);
    }
    batcher_sort16_u64(K);
  } else {
    // slow: collect all candidates with trunc <= tau, exact sort, keep 16.
    unsigned char* myb =
        reinterpret_cast<unsigned char*>(ubuf) + (unsigned)threadIdx.x * EPC;
    int cnt = 0;
#pragma unroll 4
    for (int m = 0; m < QCH; ++m) {
      float4 q = xs[cbase + m];
      int tb = __float_as_int(d2_ref(q, ppx, ppy, ppz, psq)) & 0xFFFFFF00;
      if (tb <= tau) {
        myb[cnt < EPC - 1 ? cnt : EPC - 1] = (unsigned char)m;
        ++cnt;
      }
    }
    u64 KK[32];
#pragma unroll
    for (int j = 0; j < EPC; ++j) {
      int loc = cbase + myb[j];  // u8 always < QCH; garbage past cnt masked
      float4 q = xs[loc];
      float d2 = d2_ref(q, ppx, ppy, ppz, psq);
      u64 k = pack_key(d2, s * CHUNK + loc);
      KK[j] = (j < cnt) ? k : ~0ull;
    }
#pragma unroll
    for (int j = EPC; j < 32; ++j) KK[j] = ~0ull;
    bitonic_sort32(KK);
#pragma unroll
    for (int j = 0; j < 16; ++j) K[j] = KK[j];
  }

  // ---- combine quarters: chain q1,q2,q3 stage -> q0 merges ----
  __syncthreads();  // scratch lifetime ends; staging view reuses ubuf
  u64(*L)[PTILE] = reinterpret_cast<u64(*)[PTILE]>(ubuf);
#pragma unroll 1
  for (int r = 1; r <= 3; ++r) {
    if (q4 == r) {
#pragma unroll
      for (int j = 0; j < 16; ++j) L[j][p] = K[j];
    }
    __syncthreads();
    if (q4 == 0) {
      u64 A64[16];
#pragma unroll
      for (int j = 0; j < 16; ++j) A64[j] = L[j][p];
      merge_keep16(K, A64);
    }
    __syncthreads();
  }
  if (q4 == 0) {
    u64* pb = pkey + ((size_t)(b * SPLIT + s) * KNN) * NPTS + n;
#pragma unroll
    for (int j = 0; j < 16; ++j) pb[(size_t)j * NPTS] = K[j];
  }
}

// ---------------------------------------------------------------------------
// Kernel 1b: merge SPLIT sorted key lists -> global top-16, then fp32 score
// with numpy's pairwise order. Keys unique -> order of merging irrelevant ->
// exactness holds. Also zeroes the rank counters.
// grid: BATCH*NPTS/64 = 512 blocks x 64 thr (covers all 256 CUs).
// ---------------------------------------------------------------------------
__global__ __launch_bounds__(64) void merge_score_kernel(
    const float* __restrict__ x, const u64* __restrict__ pkey,
    float* __restrict__ score, int* __restrict__ cnt) {
  const int b = blockIdx.x / (NPTS / 64);
  const int n = (blockIdx.x % (NPTS / 64)) * 64 + threadIdx.x;

  cnt[(size_t)b * NPTS + n] = 0;  // zero rank counters (was zero_kernel)

  u64 T[16];
  {
    const u64* pb = pkey + ((size_t)(b * SPLIT + 0) * KNN) * NPTS + n;
#pragma unroll
    for (int j = 0; j < 16; ++j) T[j] = pb[(size_t)j * NPTS];
  }
#pragma unroll
  for (int s = 1; s < SPLIT; ++s) {
    const u64* pb = pkey + ((size_t)(b * SPLIT + s) * KNN) * NPTS + n;
    u64 A[16];
#pragma unroll
    for (int j = 0; j < 16; ++j) A[j] = pb[(size_t)j * NPTS];
    merge_keep16(T, A);
  }

  const float* xb = x + (size_t)b * 3 * NPTS;
  float ppx = xb[n];
  float ppy = xb[NPTS + n];
  float ppz = xb[2 * NPTS + n];

  float nx[KNN], ny[KNN], nz[KNN];
#pragma unroll
  for (int j = 0; j < KNN; ++j) {
    int idx = (int)(unsigned)T[j];
    nx[j] = xb[idx];
    ny[j] = xb[NPTS + idx];
    nz[j] = xb[2 * NPTS + idx];
  }

  // numpy fp32 pairwise sum over (3,16): per d, r_j = a_j + a_{j+8},
  // P_d = ((r0+r1)+(r2+r3)) + ((r4+r5)+(r6+r7)); score = (P0+P1)+P2.
  float P[3];
#pragma unroll
  for (int d = 0; d < 3; ++d) {
    const float pc = (d == 0) ? ppx : ((d == 1) ? ppy : ppz);
    float r[8];
#pragma unroll
    for (int j = 0; j < 8; ++j) {
      float c0 = (d == 0) ? nx[j] : ((d == 1) ? ny[j] : nz[j]);
      float c1 = (d == 0) ? nx[j + 8] : ((d == 1) ? ny[j + 8] : nz[j + 8]);
      float e0 = __fsub_rn(c0, pc);
      float e1 = __fsub_rn(c1, pc);
      r[j] = __fadd_rn(__fmul_rn(e0, e0), __fmul_rn(e1, e1));
    }
    float t0 = __fadd_rn(r[0], r[1]);
    float t1 = __fadd_rn(r[2], r[3]);
    float t2 = __fadd_rn(r[4], r[5]);
    float t3 = __fadd_rn(r[6], r[7]);
    P[d] = __fadd_rn(__fadd_rn(t0, t1), __fadd_rn(t2, t3));
  }
  score[(size_t)b * NPTS + n] =
      __fadd_rn(__fadd_rn(P[0], P[1]), P[2]);
}

// ---------------------------------------------------------------------------
// Kernel 2b: partial counting rank over an m-chunk, atomicAdd into cnt.
// rank(n) = #{m : s[m]>s[n] or (s[m]==s[n] and m<n)} == stable desc argsort.
// ---------------------------------------------------------------------------
__global__ __launch_bounds__(256) void rank_partial_kernel(
    const float* __restrict__ score, int* __restrict__ cnt) {
  const int s = blockIdx.x % RSPLIT;
  const int ntile = (blockIdx.x / RSPLIT) % (NPTS / 256);
  const int b = blockIdx.x / (RSPLIT * (NPTS / 256));
  __shared__ float ss[RCHUNK];

  const float* sb = score + (size_t)b * NPTS;
  for (int i = threadIdx.x; i < RCHUNK; i += 256)
    ss[i] = sb[s * RCHUNK + i];

  const int n = ntile * 256 + threadIdx.x;
  const float sn = sb[n];
  __syncthreads();

  int c = 0;
#pragma unroll 8
  for (int mm = 0; mm < RCHUNK; ++mm) {
    float sm = ss[mm];
    int gm = s * RCHUNK + mm;
    c += (sm > sn) || (sm == sn && gm < n);
  }
  atomicAdd(&cnt[(size_t)b * NPTS + n], c);
}

// ---------------------------------------------------------------------------
// Kernel 2c: scatter selected points into rank order.
// ---------------------------------------------------------------------------
__global__ __launch_bounds__(256) void rank_scatter_kernel(
    const int* __restrict__ cnt, int* __restrict__ sel, int npts) {
  int t = blockIdx.x * 256 + threadIdx.x;  // over BATCH*NPTS
  int b = t / NPTS;
  int n = t % NPTS;
  int c = cnt[t];
  if (c < npts) sel[(size_t)b * npts + c] = n;
}

// ---------------------------------------------------------------------------
// Kernel 3: gather xyz then features into the concatenated flat output.
// ---------------------------------------------------------------------------
__global__ __launch_bounds__(256) void gather_kernel(
    const float* __restrict__ x, const float* __restrict__ y,
    const int* __restrict__ sel, float* __restrict__ out, int npts,
    int total0, int total) {
  int tid = blockIdx.x * blockDim.x + threadIdx.x;
  if (tid >= total) return;
  if (tid < total0) {
    int j = tid % npts;
    int rest = tid / npts;
    int d = rest % 3;
    int b = rest / 3;
    int src = sel[b * npts + j];
    out[tid] = x[((size_t)b * 3 + d) * NPTS + src];
  } else {
    int t = tid - total0;
    int j = t % npts;
    int rest = t / npts;
    int c = rest % CHAN;
    int b = rest / CHAN;
    int src = sel[b * npts + j];
    out[tid] = y[((size_t)b * CHAN + c) * NPTS + src];
  }
}

extern "C" void kernel_launch(void* const* d_in, const int* in_sizes, int n_in,
                              void* d_out, int out_size, void* d_ws,
                              size_t ws_size, hipStream_t stream) {
  const float* x = (const float*)d_in[0];
  const float* y = (const float*)d_in[1];
  float* out = (float*)d_out;

  const int npts = out_size / (BATCH * (3 + CHAN));

  // workspace layout:
  char* w = (char*)d_ws;
  u64* pkey = (u64*)w;                       // B*S*16*N u64 = 16.78 MB
  w += sizeof(u64) * (size_t)BATCH * SPLIT * KNN * NPTS;
  float* score = (float*)w;                  // B*N f32
  w += sizeof(float) * (size_t)BATCH * NPTS;
  int* cnt = (int*)w;                        // B*N i32
  w += sizeof(int) * (size_t)BATCH * NPTS;
  int* sel = (int*)w;                        // B*npts i32

  knn_partial_kernel<<<BATCH * (NPTS / PTILE) * SPLIT, 512, 0, stream>>>(
      x, pkey);
  merge_score_kernel<<<BATCH * NPTS / 64, 64, 0, stream>>>(x, pkey, score,
                                                           cnt);
  rank_partial_kernel<<<BATCH * (NPTS / 256) * RSPLIT, 256, 0, stream>>>(
      score, cnt);
  rank_scatter_kernel<<<BATCH * NPTS / 256, 256, 0, stream>>>(cnt, sel, npts);

  const int total0 = BATCH * 3 * npts;
  gather_kernel<<<(out_size + 255) / 256, 256, 0, stream>>>(
      x, y, sel, out, npts, total0, out_size);
}

// Round 10
// 246.887 us; speedup vs baseline: 1.1841x; 1.0130x over previous
//
#include <hip/hip_runtime.h>
#include <math.h>

#define BATCH 8
#define NPTS 4096
#define CHAN 128
#define KNN 16
#define SPLIT 4
#define CHUNK (NPTS / SPLIT)   // 1024 candidates per chunk-block
#define ISPLIT 4               // internal candidate split (4 quarters)
#define QCH (CHUNK / ISPLIT)   // 256 candidates per thread
#define PTILE 128              // points per block
#define EPC 24                 // slow-path survivor buffer capacity
#define RSPLIT 4
#define RCHUNK (NPTS / RSPLIT) // 1024 scores, 4 KB LDS

typedef unsigned long long u64;

// Monotone key: ascending u64 == (d2 ascending, idx ascending).
// Ties in d2 break toward lower index == lax.top_k stable order.
__device__ __forceinline__ u64 pack_key(float d2, int idx) {
  unsigned b = __float_as_uint(d2);
  b ^= (unsigned)((int)b >> 31) | 0x80000000u;  // order-preserving fp32 map
  return ((u64)b << 32) | (unsigned)idx;
}

// Reference d2: inner = ((x0*y0 + x1*y1) + x2*y2) fp32 no-fma (numpy einsum
// order); d2 = (sq_n + sq_m) - 2*inner. Bit-exact vs JAX reference.
__device__ __forceinline__ float d2_ref(float4 q, float ppx, float ppy,
                                        float ppz, float psq) {
  float inner = __fadd_rn(__fadd_rn(__fmul_rn(ppx, q.x), __fmul_rn(ppy, q.y)),
                          __fmul_rn(ppz, q.z));
  return __fsub_rn(__fadd_rn(psq, q.w), __fmul_rn(2.0f, inner));
}

// ----- u64 compare-exchange machinery (epilogues + k1b) --------------------
__device__ __forceinline__ void ce_asc(u64& x, u64& y) {
  bool sw = y < x;
  u64 lo = sw ? y : x;
  u64 hi = sw ? x : y;
  x = lo;
  y = hi;
}

// Batcher merge-exchange sort of 16 u64 keys, ascending. 63 CE.
__device__ __forceinline__ void batcher_sort16_u64(u64 a[16]) {
#define CE(i, j) ce_asc(a[i], a[j])
  CE(0, 8); CE(1, 9); CE(2, 10); CE(3, 11);
  CE(4, 12); CE(5, 13); CE(6, 14); CE(7, 15);
  CE(0, 4); CE(1, 5); CE(2, 6); CE(3, 7);
  CE(8, 12); CE(9, 13); CE(10, 14); CE(11, 15);
  CE(4, 8); CE(5, 9); CE(6, 10); CE(7, 11);
  CE(0, 2); CE(1, 3); CE(4, 6); CE(5, 7);
  CE(8, 10); CE(9, 11); CE(12, 14); CE(13, 15);
  CE(2, 8); CE(3, 9); CE(6, 12); CE(7, 13);
  CE(2, 4); CE(3, 5); CE(6, 8); CE(7, 9); CE(10, 12); CE(11, 13);
  CE(0, 1); CE(2, 3); CE(4, 5); CE(6, 7);
  CE(8, 9); CE(10, 11); CE(12, 13); CE(14, 15);
  CE(1, 8); CE(3, 10); CE(5, 12); CE(7, 14);
  CE(1, 4); CE(3, 6); CE(5, 8); CE(7, 10); CE(9, 12); CE(11, 14);
  CE(1, 2); CE(3, 4); CE(5, 6); CE(7, 8); CE(9, 10); CE(11, 12); CE(13, 14);
#undef CE
}

// Bitonic sort of 32 u64 keys, ascending. 240 CE (slow path only).
__device__ __forceinline__ void bitonic_sort32(u64 a[32]) {
#pragma unroll
  for (int k = 2; k <= 32; k <<= 1) {
#pragma unroll
    for (int j = k >> 1; j > 0; j >>= 1) {
#pragma unroll
      for (int i = 0; i < 32; ++i) {
        int l = i ^ j;
        if (l > i) {
          if ((i & k) == 0) ce_asc(a[i], a[l]);
          else              ce_asc(a[l], a[i]);
        }
      }
    }
  }
}

// T, A both sorted ascending. T <- lowest-16 of (T ∪ A), sorted ascending.
__device__ __forceinline__ void merge_keep16(u64 T[16], const u64 A[16]) {
  u64 nt[16];
#pragma unroll
  for (int i = 0; i < 16; ++i) {
    u64 a = A[15 - i];
    nt[i] = (a < T[i]) ? a : T[i];
  }
#pragma unroll
  for (int j = 8; j > 0; j >>= 1) {
#pragma unroll
    for (int i = 0; i < 16; ++i) {
      int l = i ^ j;
      if (l > i) ce_asc(nt[i], nt[l]);
    }
  }
#pragma unroll
  for (int i = 0; i < 16; ++i) T[i] = nt[i];
}

// ----- i32 packed-key machinery (hot phase 1) ------------------------------
// Packed key = (d2bits & ~255) | local_idx (8-bit). Signed-i32 ascending ==
// (trunc(d2), idx) ascending for all d2 >= 0 (negatives sort below all
// positives -> always selected -> exact epilogue fixes internal order).
// CE = v_min_i32 + v_max_i32 = 2 VALU.
__device__ __forceinline__ void ce_i32(int& x, int& y) {
  int lo = (x < y) ? x : y;
  int hi = (x < y) ? y : x;
  x = lo;
  y = hi;
}

// Batcher merge-exchange sort of 16 i32 keys, ascending. 63 CE.
__device__ __forceinline__ void batcher_sort16_i32(int a[16]) {
#define CE(i, j) ce_i32(a[i], a[j])
  CE(0, 8); CE(1, 9); CE(2, 10); CE(3, 11);
  CE(4, 12); CE(5, 13); CE(6, 14); CE(7, 15);
  CE(0, 4); CE(1, 5); CE(2, 6); CE(3, 7);
  CE(8, 12); CE(9, 13); CE(10, 14); CE(11, 15);
  CE(4, 8); CE(5, 9); CE(6, 10); CE(7, 11);
  CE(0, 2); CE(1, 3); CE(4, 6); CE(5, 7);
  CE(8, 10); CE(9, 11); CE(12, 14); CE(13, 15);
  CE(2, 8); CE(3, 9); CE(6, 12); CE(7, 13);
  CE(2, 4); CE(3, 5); CE(6, 8); CE(7, 9); CE(10, 12); CE(11, 13);
  CE(0, 1); CE(2, 3); CE(4, 5); CE(6, 7);
  CE(8, 9); CE(10, 11); CE(12, 13); CE(14, 15);
  CE(1, 8); CE(3, 10); CE(5, 12); CE(7, 14);
  CE(1, 4); CE(3, 6); CE(5, 8); CE(7, 10); CE(9, 12); CE(11, 14);
  CE(1, 2); CE(3, 4); CE(5, 6); CE(7, 8); CE(9, 10); CE(11, 12); CE(13, 14);
#undef CE
}

// T, A sorted ascending (i32). T <- lowest-16 of (T ∪ A). 80 VALU.
__device__ __forceinline__ void merge_keep16_i32(int T[16], const int A[16]) {
  int nt[16];
#pragma unroll
  for (int i = 0; i < 16; ++i) {
    int a = A[15 - i];
    nt[i] = (a < T[i]) ? a : T[i];
  }
#pragma unroll
  for (int j = 8; j > 0; j >>= 1) {
#pragma unroll
    for (int i = 0; i < 16; ++i) {
      int l = i ^ j;
      if (l > i) ce_i32(nt[i], nt[l]);
    }
  }
#pragma unroll
  for (int i = 0; i < 16; ++i) T[i] = nt[i];
}

// ---------------------------------------------------------------------------
// Kernel 1a: per-chunk 16-NN partials as sorted u64 keys.
// FROZEN at the R9 form (best measured ~134 us): four latency-hiding levers
// (waves, named prefetch, unroll, uncapped occupancy) all failed to move it;
// further edits here need a new mechanism, not a new knob.
// Exactness: tau superset + exact r17 guard; fast path rebuilds exact u64
// keys; slow path rescans {trunc <= tau} -> bit-identical to full-u64 path.
// ---------------------------------------------------------------------------
__global__ __launch_bounds__(512) void knn_partial_kernel(
    const float* __restrict__ x, u64* __restrict__ pkey) {
  const int s = blockIdx.x % SPLIT;
  const int ntile = (blockIdx.x / SPLIT) % (NPTS / PTILE);
  const int b = blockIdx.x / (SPLIT * (NPTS / PTILE));
  const int p = threadIdx.x & (PTILE - 1);
  const int q4 = threadIdx.x >> 7;  // quarter 0..3 (wave-uniform: 2 waves/q)
  __shared__ float4 xs[CHUNK];        // 16 KB (x, y, z, sq)
  __shared__ u64 ubuf[2048];          // 16 KB: u8 scratch(12K) ∪ staging(16K)

  const float* xb = x + (size_t)b * 3 * NPTS;
  for (int i = threadIdx.x; i < CHUNK; i += 512) {
    int gm = s * CHUNK + i;
    float px = xb[gm];
    float py = xb[NPTS + gm];
    float pz = xb[2 * NPTS + gm];
    float sq = __fadd_rn(__fadd_rn(__fmul_rn(px, px), __fmul_rn(py, py)),
                         __fmul_rn(pz, pz));
    xs[i] = make_float4(px, py, pz, sq);
  }

  const int n = ntile * PTILE + p;
  float ppx = xb[n];
  float ppy = xb[NPTS + n];
  float ppz = xb[2 * NPTS + n];
  float psq = __fadd_rn(__fadd_rn(__fmul_rn(ppx, ppx), __fmul_rn(ppy, ppy)),
                        __fmul_rn(ppz, ppz));
  __syncthreads();

  const int cbase = q4 * QCH;

  // ---- Phase 1: top-16 packed keys + exact 17th (r17) ----
  int T[16];
#pragma unroll
  for (int i = 0; i < 16; ++i) T[i] = 0x7FFFFFFF;  // sentinel > any real key
  int r17 = 0x7FFFFFFF;

#pragma unroll 1
  for (int base = 0; base < QCH; base += 16) {
    int A[16];
#pragma unroll
    for (int t = 0; t < 16; ++t) {
      float4 q = xs[cbase + base + t];
      int bits = __float_as_int(d2_ref(q, ppx, ppy, ppz, psq));
      A[t] = (bits & 0xFFFFFF00) | (base + t);
    }
    batcher_sort16_i32(A);
    // 17th smallest of (T ∪ A), both sorted: min_i max(T[i], A[15-i])
    int u[16];
#pragma unroll
    for (int i = 0; i < 16; ++i) {
      int a = A[15 - i];
      u[i] = (T[i] < a) ? a : T[i];  // max
    }
#pragma unroll
    for (int w = 8; w > 0; w >>= 1) {
#pragma unroll
      for (int i = 0; i < 16; ++i) {
        if (i < w) u[i] = (u[i] < u[i + w]) ? u[i] : u[i + w];  // min
      }
    }
    r17 = (r17 < u[0]) ? r17 : u[0];
    merge_keep16_i32(T, A);
  }

  const int tau = T[15] & 0xFFFFFF00;
  const bool slow = ((r17 & 0xFFFFFF00) == tau);

  // ---- Epilogue: exact u64 top-16 keys ----
  u64 K[16];
  if (!slow) {
    // fast: T is the exact top-16 set; rebuild exact keys, sort.
#pragma unroll
    for (int j = 0; j < 16; ++j) {
      int loc = cbase + (T[j] & 255);
      float4 q = xs[loc];
      float d2 = d2_ref(q, ppx, ppy, ppz, psq);
      K[j] = pack_key(d2, s * CHUNK + loc);
    }
    batcher_sort16_u64(K);
  } else {
    // slow: collect all candidates with trunc <= tau, exact sort, keep 16.
    unsigned char* myb =
        reinterpret_cast<unsigned char*>(ubuf) + (unsigned)threadIdx.x * EPC;
    int cnt = 0;
#pragma unroll 4
    for (int m = 0; m < QCH; ++m) {
      float4 q = xs[cbase + m];
      int tb = __float_as_int(d2_ref(q, ppx, ppy, ppz, psq)) & 0xFFFFFF00;
      if (tb <= tau) {
        myb[cnt < EPC - 1 ? cnt : EPC - 1] = (unsigned char)m;
        ++cnt;
      }
    }
    u64 KK[32];
#pragma unroll
    for (int j = 0; j < EPC; ++j) {
      int loc = cbase + myb[j];  // u8 always < QCH; garbage past cnt masked
      float4 q = xs[loc];
      float d2 = d2_ref(q, ppx, ppy, ppz, psq);
      u64 k = pack_key(d2, s * CHUNK + loc);
      KK[j] = (j < cnt) ? k : ~0ull;
    }
#pragma unroll
    for (int j = EPC; j < 32; ++j) KK[j] = ~0ull;
    bitonic_sort32(KK);
#pragma unroll
    for (int j = 0; j < 16; ++j) K[j] = KK[j];
  }

  // ---- combine quarters: chain q1,q2,q3 stage -> q0 merges ----
  __syncthreads();  // scratch lifetime ends; staging view reuses ubuf
  u64(*L)[PTILE] = reinterpret_cast<u64(*)[PTILE]>(ubuf);
#pragma unroll 1
  for (int r = 1; r <= 3; ++r) {
    if (q4 == r) {
#pragma unroll
      for (int j = 0; j < 16; ++j) L[j][p] = K[j];
    }
    __syncthreads();
    if (q4 == 0) {
      u64 A64[16];
#pragma unroll
      for (int j = 0; j < 16; ++j) A64[j] = L[j][p];
      merge_keep16(K, A64);
    }
    __syncthreads();
  }
  if (q4 == 0) {
    u64* pb = pkey + ((size_t)(b * SPLIT + s) * KNN) * NPTS + n;
#pragma unroll
    for (int j = 0; j < 16; ++j) pb[(size_t)j * NPTS] = K[j];
  }
}

// ---------------------------------------------------------------------------
// Kernel 1b: merge SPLIT sorted key lists -> global top-16, then fp32 score.
// Round-10 restructure: 4 THREADS PER POINT (lane s = t&3 owns list s).
// Was: 1 thread/point, 64 strided loads + 3 merges, 512 waves total = half
// the device idle. Now: 16 loads/thread, then two shfl_xor(1,2) +
// merge_keep16 rounds -- all 4 lanes converge to the identical sorted global
// top-16 (merge_keep16 output depends only on the SET; keys unique). 2048
// waves. Scoring: lane s in {0,1,2} computes P_s for its dim (16 gathers),
// recombined on lane 0 as (P0+P1)+P2 -- numpy pairwise order bit-exact.
// Also zeroes the rank counters. grid: BATCH*(NPTS/64) = 512 blocks x 256.
// ---------------------------------------------------------------------------
__global__ __launch_bounds__(256) void merge_score_kernel(
    const float* __restrict__ x, const u64* __restrict__ pkey,
    float* __restrict__ score, int* __restrict__ cnt) {
  const int tile = blockIdx.x % (NPTS / 64);
  const int b = blockIdx.x / (NPTS / 64);
  const int g = threadIdx.x >> 2;  // point within tile [0,64)
  const int s = threadIdx.x & 3;   // split list
  const int n = tile * 64 + g;

  if (threadIdx.x < 64)
    cnt[(size_t)b * NPTS + tile * 64 + threadIdx.x] = 0;

  // load own sorted list (16 loads, 4 interleaved coalesced streams/wave)
  u64 T[16];
  {
    const u64* pb = pkey + ((size_t)(b * SPLIT + s) * KNN) * NPTS + n;
#pragma unroll
    for (int j = 0; j < 16; ++j) T[j] = pb[(size_t)j * NPTS];
  }

  // cross-lane merge within the 4-lane group: xor 1 then xor 2.
  u64 A[16];
#pragma unroll
  for (int j = 0; j < 16; ++j)
    A[j] = (u64)__shfl_xor((long long)T[j], 1);
  merge_keep16(T, A);
#pragma unroll
  for (int j = 0; j < 16; ++j)
    A[j] = (u64)__shfl_xor((long long)T[j], 2);
  merge_keep16(T, A);
  // all 4 lanes now hold the identical global sorted top-16.

  const float* xb = x + (size_t)b * 3 * NPTS;
  float P = 0.0f;
  if (s < 3) {
    const float* xd = xb + (size_t)s * NPTS;
    const float pc = xd[n];
    float r[8];
#pragma unroll
    for (int j = 0; j < 8; ++j) {
      float c0 = xd[(int)(unsigned)T[j]];
      float c1 = xd[(int)(unsigned)T[j + 8]];
      float e0 = __fsub_rn(c0, pc);
      float e1 = __fsub_rn(c1, pc);
      r[j] = __fadd_rn(__fmul_rn(e0, e0), __fmul_rn(e1, e1));
    }
    float t0 = __fadd_rn(r[0], r[1]);
    float t1 = __fadd_rn(r[2], r[3]);
    float t2 = __fadd_rn(r[4], r[5]);
    float t3 = __fadd_rn(r[6], r[7]);
    P = __fadd_rn(__fadd_rn(t0, t1), __fadd_rn(t2, t3));
  }
  float Pa = __shfl_xor(P, 1);  // lane0 <- P1
  float Pb = __shfl_xor(P, 2);  // lane0 <- P2
  if (s == 0)
    score[(size_t)b * NPTS + n] = __fadd_rn(__fadd_rn(P, Pa), Pb);
}

// ---------------------------------------------------------------------------
// Kernel 2b: partial counting rank over an m-chunk, atomicAdd into cnt.
// rank(n) = #{m : s[m]>s[n] or (s[m]==s[n] and m<n)} == stable desc argsort.
// Round-10: LDS feed vectorized to float4 (1 broadcast ds_read_b128 per 4
// candidates instead of 4 ds_read_b32). Comparison semantics unchanged.
// ---------------------------------------------------------------------------
__global__ __launch_bounds__(256) void rank_partial_kernel(
    const float* __restrict__ score, int* __restrict__ cnt) {
  const int s = blockIdx.x % RSPLIT;
  const int ntile = (blockIdx.x / RSPLIT) % (NPTS / 256);
  const int b = blockIdx.x / (RSPLIT * (NPTS / 256));
  __shared__ float4 sv[RCHUNK / 4];  // 4 KB

  const float* sb = score + (size_t)b * NPTS;
  const float4* sb4 = reinterpret_cast<const float4*>(sb + s * RCHUNK);
  for (int i = threadIdx.x; i < RCHUNK / 4; i += 256) sv[i] = sb4[i];

  const int n = ntile * 256 + threadIdx.x;
  const float sn = sb[n];
  __syncthreads();

  int c = 0;
#pragma unroll 4
  for (int v = 0; v < RCHUNK / 4; ++v) {
    float4 f = sv[v];
    int gm = s * RCHUNK + 4 * v;
    c += (f.x > sn) || (f.x == sn && gm < n);
    c += (f.y > sn) || (f.y == sn && gm + 1 < n);
    c += (f.z > sn) || (f.z == sn && gm + 2 < n);
    c += (f.w > sn) || (f.w == sn && gm + 3 < n);
  }
  atomicAdd(&cnt[(size_t)b * NPTS + n], c);
}

// ---------------------------------------------------------------------------
// Kernel 2c: scatter selected points into rank order.
// ---------------------------------------------------------------------------
__global__ __launch_bounds__(256) void rank_scatter_kernel(
    const int* __restrict__ cnt, int* __restrict__ sel, int npts) {
  int t = blockIdx.x * 256 + threadIdx.x;  // over BATCH*NPTS
  int b = t / NPTS;
  int n = t % NPTS;
  int c = cnt[t];
  if (c < npts) sel[(size_t)b * npts + c] = n;
}

// ---------------------------------------------------------------------------
// Kernel 3: gather xyz then features into the concatenated flat output.
// ---------------------------------------------------------------------------
__global__ __launch_bounds__(256) void gather_kernel(
    const float* __restrict__ x, const float* __restrict__ y,
    const int* __restrict__ sel, float* __restrict__ out, int npts,
    int total0, int total) {
  int tid = blockIdx.x * blockDim.x + threadIdx.x;
  if (tid >= total) return;
  if (tid < total0) {
    int j = tid % npts;
    int rest = tid / npts;
    int d = rest % 3;
    int b = rest / 3;
    int src = sel[b * npts + j];
    out[tid] = x[((size_t)b * 3 + d) * NPTS + src];
  } else {
    int t = tid - total0;
    int j = t % npts;
    int rest = t / npts;
    int c = rest % CHAN;
    int b = rest / CHAN;
    int src = sel[b * npts + j];
    out[tid] = y[((size_t)b * CHAN + c) * NPTS + src];
  }
}

extern "C" void kernel_launch(void* const* d_in, const int* in_sizes, int n_in,
                              void* d_out, int out_size, void* d_ws,
                              size_t ws_size, hipStream_t stream) {
  const float* x = (const float*)d_in[0];
  const float* y = (const float*)d_in[1];
  float* out = (float*)d_out;

  const int npts = out_size / (BATCH * (3 + CHAN));

  // workspace layout:
  char* w = (char*)d_ws;
  u64* pkey = (u64*)w;                       // B*S*16*N u64 = 16.78 MB
  w += sizeof(u64) * (size_t)BATCH * SPLIT * KNN * NPTS;
  float* score = (float*)w;                  // B*N f32
  w += sizeof(float) * (size_t)BATCH * NPTS;
  int* cnt = (int*)w;                        // B*N i32
  w += sizeof(int) * (size_t)BATCH * NPTS;
  int* sel = (int*)w;                        // B*npts i32

  knn_partial_kernel<<<BATCH * (NPTS / PTILE) * SPLIT, 512, 0, stream>>>(
      x, pkey);
  merge_score_kernel<<<BATCH * (NPTS / 64), 256, 0, stream>>>(x, pkey, score,
                                                              cnt);
  rank_partial_kernel<<<BATCH * (NPTS / 256) * RSPLIT, 256, 0, stream>>>(
      score, cnt);
  rank_scatter_kernel<<<BATCH * NPTS / 256, 256, 0, stream>>>(cnt, sel, npts);

  const int total0 = BATCH * 3 * npts;
  gather_kernel<<<(out_size + 255) / 256, 256, 0, stream>>>(
      x, y, sel, out, npts, total0, out_size);
}